// Round 1
// baseline (47.526 us; speedup 1.0000x reference)
//
#include <hip/hip_runtime.h>
#include <hip/hip_bf16.h>

typedef float f32x4 __attribute__((ext_vector_type(4)));
typedef __bf16 bf16x8 __attribute__((ext_vector_type(8)));

#define INF   8192          // in_features
#define FOLDS 127
#define LOCAL 128
#define OUTF  (FOLDS * LOCAL)  // 16256
#define BM    128

__global__ __launch_bounds__(256, 2)
void local_linear_kernel(const float* __restrict__ x,
                         const float* __restrict__ W,
                         const float* __restrict__ bias,
                         float* __restrict__ out)
{
    // 64 KiB LDS: A tile (x window, 128x128 bf16) + B tile (W fold, 128x128 bf16)
    __shared__ __align__(16) __bf16 As[128 * 128];
    __shared__ __align__(16) __bf16 Bs[128 * 128];

    const int mt = blockIdx.x;   // batch tile 0..15
    const int f  = blockIdx.y;   // fold 0..126
    const int t  = threadIdx.x;  // 0..255

    const int m0 = mt * BM;
    const float* __restrict__ xg = x + (size_t)m0 * INF + (size_t)f * 64;
    const float* __restrict__ Wf = W + (size_t)f * (LOCAL * 128);

    // ---- stage x tile -> As (bf16, XOR-swizzled rows, k contiguous) ----
    #pragma unroll
    for (int it = 0; it < 8; ++it) {
        const int e   = it * 2048 + t * 8;
        const int row = e >> 7;        // 0..127 (batch row within tile)
        const int col = e & 127;       // k
        const float* g = xg + (size_t)row * INF + col;
        f32x4 v0 = *(const f32x4*)g;
        f32x4 v1 = *(const f32x4*)(g + 4);
        bf16x8 w;
        w[0] = (__bf16)v0[0]; w[1] = (__bf16)v0[1];
        w[2] = (__bf16)v0[2]; w[3] = (__bf16)v0[3];
        w[4] = (__bf16)v1[0]; w[5] = (__bf16)v1[1];
        w[6] = (__bf16)v1[2]; w[7] = (__bf16)v1[3];
        const int byte = (row * 256 + col * 2) ^ ((row & 7) << 4);
        *(bf16x8*)((char*)As + byte) = w;
    }
    // ---- stage W fold -> Bs (same layout; W[f] is [l][k], k contiguous) ----
    #pragma unroll
    for (int it = 0; it < 8; ++it) {
        const int e   = it * 2048 + t * 8;
        const int row = e >> 7;        // l (output feature)
        const int col = e & 127;       // k
        const float* g = Wf + row * 128 + col;
        f32x4 v0 = *(const f32x4*)g;
        f32x4 v1 = *(const f32x4*)(g + 4);
        bf16x8 w;
        w[0] = (__bf16)v0[0]; w[1] = (__bf16)v0[1];
        w[2] = (__bf16)v0[2]; w[3] = (__bf16)v0[3];
        w[4] = (__bf16)v1[0]; w[5] = (__bf16)v1[1];
        w[6] = (__bf16)v1[2]; w[7] = (__bf16)v1[3];
        const int byte = (row * 256 + col * 2) ^ ((row & 7) << 4);
        *(bf16x8*)((char*)Bs + byte) = w;
    }
    __syncthreads();

    // ---- compute: 4 waves in 2x2 grid, each owns 64x64 of the 128x128 tile ----
    const int lane = t & 63;
    const int wid  = t >> 6;
    const int wm   = wid >> 1;       // 0..1
    const int wn   = wid & 1;        // 0..1
    const int r16  = lane & 15;
    const int kq   = lane >> 4;      // 0..3

    f32x4 acc[4][4];
    #pragma unroll
    for (int i = 0; i < 4; ++i)
        #pragma unroll
        for (int j = 0; j < 4; ++j)
            acc[i][j] = (f32x4){0.f, 0.f, 0.f, 0.f};

    #pragma unroll
    for (int ks = 0; ks < 4; ++ks) {
        const int kof = ks * 32 + kq * 8;   // per-lane k offset (8 contiguous bf16)
        bf16x8 a[4], b[4];
        #pragma unroll
        for (int i = 0; i < 4; ++i) {
            const int row  = wm * 64 + i * 16 + r16;   // m index
            const int byte = (row * 256 + kof * 2) ^ ((row & 7) << 4);
            a[i] = *(const bf16x8*)((const char*)As + byte);
        }
        #pragma unroll
        for (int j = 0; j < 4; ++j) {
            const int row  = wn * 64 + j * 16 + r16;   // n index
            const int byte = (row * 256 + kof * 2) ^ ((row & 7) << 4);
            b[j] = *(const bf16x8*)((const char*)Bs + byte);
        }
        #pragma unroll
        for (int i = 0; i < 4; ++i)
            #pragma unroll
            for (int j = 0; j < 4; ++j)
                acc[i][j] = __builtin_amdgcn_mfma_f32_16x16x32_bf16(a[i], b[j], acc[i][j], 0, 0, 0);
    }

    // ---- epilogue: + bias, store fp32 ----
    float bv[4];
    #pragma unroll
    for (int j = 0; j < 4; ++j)
        bv[j] = bias[f * LOCAL + wn * 64 + j * 16 + r16];

    #pragma unroll
    for (int i = 0; i < 4; ++i) {
        const int mrow = m0 + wm * 64 + i * 16 + kq * 4;  // C/D: m = (lane>>4)*4 + reg
        #pragma unroll
        for (int j = 0; j < 4; ++j) {
            const int ncol = f * LOCAL + wn * 64 + j * 16 + r16;  // C/D: n = lane&15
            float* o = out + (size_t)mrow * OUTF + ncol;
            #pragma unroll
            for (int r = 0; r < 4; ++r)
                o[(size_t)r * OUTF] = acc[i][j][r] + bv[j];
        }
    }
}

extern "C" void kernel_launch(void* const* d_in, const int* in_sizes, int n_in,
                              void* d_out, int out_size, void* d_ws, size_t ws_size,
                              hipStream_t stream) {
    const float* x    = (const float*)d_in[0];
    const float* W    = (const float*)d_in[1];
    const float* bias = (const float*)d_in[2];
    float* out        = (float*)d_out;

    dim3 grid(2048 / BM, FOLDS);   // 16 x 127
    dim3 block(256);
    local_linear_kernel<<<grid, block, 0, stream>>>(x, W, bias, out);
}